// Round 2
// 1294.941 us; speedup vs baseline: 1.2814x; 1.2814x over previous
//
#include <hip/hip_runtime.h>

// THAN_45664092291649 — MI355X. Round 4.
// Dtype-agnostic (device-side sniff of time_freq[0]: f32 word 0x3F800000 vs bf16 pair).
// Algebra: Wrel folded into K/V weights (BT, k-dim 512 with etype zero-masking);
// query folded into K-proj (qB = qh @ BT_k); attention weights folded into V-proj
// (o = (a^T A) @ BT_v^T); Wo folded into MLP (WoM1). The gathered A matrix
// [40 x 512] exists only in LDS — no giant intermediate.
// R4: attnA_k = subtiled [4x16] LDS layout + balanced __cosf fill + MFMA scores
// (m97-verified fragment layout, k-map cancellation makes it robust) + VALU aA
// with vectorized ds_read_b128 and per-group row rotation (conflict-free).
// The R3 tr-read/hi-lo pipeline is removed (semantics unverified -> wrong output).

typedef unsigned short u16;
typedef unsigned int   u32;

typedef __attribute__((ext_vector_type(8))) __bf16 bf16x8;
typedef __attribute__((ext_vector_type(4))) float  f32x4;

struct __align__(16) Meta { int node; int eidx; int et; float dt; };

__device__ __forceinline__ float bf2f(u16 u) { return __uint_as_float(((u32)u) << 16); }
__device__ __forceinline__ u16 f2bf(float f) {
  u32 x = __float_as_uint(f);
  return (u16)((x + 0x7fffu + ((x >> 16) & 1u)) >> 16);  // RNE
}
__device__ __forceinline__ u32 pk(float a, float b) { return (u32)f2bf(a) | ((u32)f2bf(b) << 16); }
__device__ __forceinline__ bool sniff_bf(const void* tf) { return *(const u32*)tf != 0x3F800000u; }
__device__ __forceinline__ float lda(const void* p, size_t i, bool bf) {
  return bf ? bf2f(((const u16*)p)[i]) : ((const float*)p)[i];
}

// subtiled LDS index: A[40][512] stored as [10][32][4][16] (u16 units)
__device__ __forceinline__ int sub_off(int r, int c) {
  return ((r >> 2) << 11) + ((c >> 4) << 6) + ((r & 3) << 4) + (c & 15);
}

// ---------- canonicalization ----------
// All weights -> one contiguous bf16 block (offsets in u16 elements):
#define oWq 0
#define oWk 294912
#define oWv 589824
#define oWo 884736
#define oWm1 1179648
#define obm1 1310720
#define oWm2 1310976
#define obm2 1343744
#define oWrel 1344000
#define oWmatch 1409536
#define obmatch 1442304
#define NW_TOTAL 1442306

__global__ void cvt_w_k(const void* Wq, const void* Wk, const void* Wv, const void* Wo,
                        const void* Wm1, const void* bm1, const void* Wm2, const void* bm2,
                        const void* Wrel, const void* Wmatch, const void* bmatch,
                        const void* tf, u16* __restrict__ dst) {
  const bool bf = sniff_bf(tf);
  int i = blockIdx.x * 256 + threadIdx.x;
  if (i >= NW_TOTAL) return;
  const void* src; int off;
  if      (i < oWk)     { src = Wq;     off = i; }
  else if (i < oWv)     { src = Wk;     off = i - oWk; }
  else if (i < oWo)     { src = Wv;     off = i - oWv; }
  else if (i < oWm1)    { src = Wo;     off = i - oWo; }
  else if (i < obm1)    { src = Wm1;    off = i - oWm1; }
  else if (i < oWm2)    { src = bm1;    off = i - obm1; }
  else if (i < obm2)    { src = Wm2;    off = i - oWm2; }
  else if (i < oWrel)   { src = bm2;    off = i - obm2; }
  else if (i < oWmatch) { src = Wrel;   off = i - oWrel; }
  else if (i < obmatch) { src = Wmatch; off = i - oWmatch; }
  else                  { src = bmatch; off = i - obmatch; }
  dst[i] = bf ? ((const u16*)src)[off] : f2bf(((const float*)src)[off]);
}

// time_freq | time_phase -> f32[256]
__global__ void cvt_tf_k(const void* tf, const void* tp, float* __restrict__ dst) {
  const bool bf = sniff_bf(tf);
  int i = threadIdx.x;
  dst[i] = (i < 128) ? lda(tf, i, bf) : lda(tp, i - 128, bf);
}

// big feature tables -> bf16; dofold sums two tables (n_feat + mem_tab)
__global__ void cvt_feat_k(const void* a, const void* b, const void* tf,
                           u16* __restrict__ dst, int n4, int dofold) {
  int t = blockIdx.x * 256 + threadIdx.x;
  if (t >= n4) return;
  const bool bf = sniff_bf(tf);
  size_t base = (size_t)t * 4;
  float va[4];
  if (bf) {
    uint2 u = *(const uint2*)((const u16*)a + base);
    va[0] = bf2f((u16)(u.x & 0xffff)); va[1] = bf2f((u16)(u.x >> 16));
    va[2] = bf2f((u16)(u.y & 0xffff)); va[3] = bf2f((u16)(u.y >> 16));
  } else {
    float4 f = *(const float4*)((const float*)a + base);
    va[0] = f.x; va[1] = f.y; va[2] = f.z; va[3] = f.w;
  }
  if (dofold) {
    float vb[4];
    if (bf) {
      uint2 u = *(const uint2*)((const u16*)b + base);
      vb[0] = bf2f((u16)(u.x & 0xffff)); vb[1] = bf2f((u16)(u.x >> 16));
      vb[2] = bf2f((u16)(u.y & 0xffff)); vb[3] = bf2f((u16)(u.y >> 16));
    } else {
      float4 f = *(const float4*)((const float*)b + base);
      vb[0] = f.x; vb[1] = f.y; vb[2] = f.z; vb[3] = f.w;
    }
    for (int i = 0; i < 4; ++i) va[i] += vb[i];
  }
  *(uint2*)(dst + base) = make_uint2(pk(va[0], va[1]), pk(va[2], va[3]));
}

// ---------- weight folds ----------
// BT[L][n(768)][k(512)]: n<384 K-col else V-col; k: [Wrel0@W, Wrel1@W, W[128:256], W[256:384]]
__global__ void build_BT_k(const u16* __restrict__ Wk, const u16* __restrict__ Wv,
                           const u16* __restrict__ Wrel, u16* __restrict__ BT) {
  int idx = blockIdx.x * 256 + threadIdx.x;
  if (idx >= 2 * 768 * 512) return;
  int L = idx / (768 * 512);
  int rem = idx - L * (768 * 512);
  int nn = rem >> 9, k = rem & 511;
  int ncol = (nn < 384) ? nn : nn - 384;
  const u16* W = ((nn < 384) ? Wk : Wv) + (size_t)L * 384 * 384;
  int region = k >> 7, kk = k & 127;
  float v;
  if (region <= 1) {
    const u16* R = Wrel + (((size_t)((L * 2 + region) * 128 + kk)) << 7);
    float acc = 0.f;
    for (int d = 0; d < 128; ++d) acc += bf2f(R[d]) * bf2f(W[d * 384 + ncol]);
    v = acc;
  } else {
    int rrow = (region == 2) ? (128 + kk) : (256 + kk);
    v = bf2f(W[rrow * 384 + ncol]);
  }
  BT[idx] = f2bf(v);
}

__global__ void build_WoM1_k(const u16* __restrict__ Wo, const u16* __restrict__ Wm1,
                             u16* __restrict__ WoM1) {
  int idx = blockIdx.x * 256 + threadIdx.x;
  if (idx >= 2 * 384 * 128) return;
  int L = idx / (384 * 128);
  int rem = idx - L * (384 * 128);
  int c = rem >> 7, j = rem & 127;
  const u16* wo = Wo + (size_t)L * 384 * 384 + (size_t)c * 384;
  const u16* wm = Wm1 + (size_t)L * 512 * 128;
  float acc = 0.f;
  for (int d = 0; d < 384; ++d) acc += bf2f(wo[d]) * bf2f(wm[d * 128 + j]);
  WoM1[idx] = f2bf(acc);
}

// qb[L][j] = sum_d cos(phase[d]) * Wq[L][256+d][j]
__global__ void build_qb_k(const u16* __restrict__ Wq, const float* __restrict__ tp,
                           float* __restrict__ qb) {
  int idx = blockIdx.x * 256 + threadIdx.x;
  if (idx >= 2 * 384) return;
  int L = idx / 384, j = idx - L * 384;
  const u16* w = Wq + (size_t)L * 384 * 384 + 256 * 384 + j;
  float acc = 0.f;
  for (int d = 0; d < 128; ++d) acc += cosf(tp[d]) * bf2f(w[d * 384]);
  qb[idx] = acc;
}

// ---------- per-row metadata (reads raw times with dtype branch) ----------
__global__ void build_meta_k(Meta* __restrict__ meta, const int* __restrict__ nd,
                             const int* __restrict__ ei, const int* __restrict__ et,
                             const void* tn, const void* ts, const void* tf,
                             int R, int mode) {
  int r = blockIdx.x * 256 + threadIdx.x;
  if (r >= R) return;
  const bool bf = sniff_bf(tf);
  int n = r / 40;
  float tsrc = (mode == 0) ? lda(ts, n, bf) : lda(ts, n & 127, bf);
  Meta m; m.node = nd[r]; m.eidx = ei[r]; m.et = et[r]; m.dt = tsrc - lda(tn, r, bf);
  meta[r] = m;
}

// src features f32 from folded nm table
__global__ void gather_src_k(const int* __restrict__ idx, const int* __restrict__ sidx,
                             const int* __restrict__ tidx, const u16* __restrict__ nm,
                             float* __restrict__ out, int total, int mode) {
  int t = blockIdx.x * 256 + threadIdx.x;
  if (t >= total) return;
  int n = t >> 7, c = t & 127;
  int node = (mode == 0) ? idx[n] : ((n < 128) ? sidx[n] : tidx[n - 128]);
  out[t] = bf2f(nm[(((size_t)node) << 7) + c]);
}

// qh[n][384] = src[n] @ Wq[0:128,:] + qb
__global__ __launch_bounds__(384) void qgemm_k(const float* __restrict__ src,
                                               const u16* __restrict__ Wq,
                                               const float* __restrict__ qb,
                                               float* __restrict__ qh) {
  __shared__ float s[128];
  const int n = blockIdx.x, j = threadIdx.x;
  if (j < 128) s[j] = src[(size_t)n * 128 + j];
  __syncthreads();
  float acc = qb[j];
  for (int c = 0; c < 128; ++c) acc += s[c] * bf2f(Wq[c * 384 + j]);
  qh[(size_t)n * 384 + j] = acc;
}

// ---------- qB = per-head qh @ BT_k  (tiled; grid {jb=4, h=4, nb}) ----------
__global__ __launch_bounds__(256) void qB_gemm_k(const float* __restrict__ qh,
                                                 const u16* __restrict__ BT,
                                                 u16* __restrict__ qB) {
  __shared__ float Qs[64][100];
  __shared__ u16 Bs[96][136];
  const int jb = blockIdx.x, h = blockIdx.y, n0 = blockIdx.z * 64;
  const int tid = threadIdx.x;
  for (int i = tid; i < 64 * 96; i += 256) {
    int r = i / 96, d = i - r * 96;
    Qs[r][d] = qh[(size_t)(n0 + r) * 384 + h * 96 + d];
  }
  for (int i = tid; i < 96 * 128; i += 256) {
    int r = i >> 7, c = i & 127;
    Bs[r][c] = BT[(size_t)(h * 96 + r) * 512 + jb * 128 + c];
  }
  __syncthreads();
  const int ty = tid >> 5, tx = tid & 31;
  float acc[8][4] = {};
  for (int d = 0; d < 96; ++d) {
    float bb[4];
    for (int i2 = 0; i2 < 4; ++i2) bb[i2] = bf2f(Bs[d][tx + 32 * i2]);
    for (int rr = 0; rr < 8; ++rr) {
      float qv = Qs[ty * 8 + rr][d];
      for (int i2 = 0; i2 < 4; ++i2) acc[rr][i2] += qv * bb[i2];
    }
  }
  for (int rr = 0; rr < 8; ++rr)
    for (int i2 = 0; i2 < 4; ++i2)
      qB[(size_t)(n0 + ty * 8 + rr) * 2048 + h * 512 + jb * 128 + tx + 32 * i2] =
          f2bf(acc[rr][i2]);
}

// ---------- per-node attention ----------
// LDS A[40][512] bf16, subtiled [10][32][4][16].
// scores: S = A @ qB^T via mfma 16x16x32 (waves 0..2, 16 rows each; cols=heads);
// softmax f32 in sc; aA = P @ A on VALU with ds_read_b128 (lane owns 8 contiguous
// cols) and per-group row rotation r = rr + 9g mod 40 (r mod 4 differs per group
// -> all 32 banks covered, conflict-free).
__global__ __launch_bounds__(256) void attnA_k(const Meta* __restrict__ meta,
                                               const u16* __restrict__ nm,
                                               const u16* __restrict__ ef,
                                               const u16* __restrict__ hfeat,
                                               const float* __restrict__ tfp,
                                               const u16* __restrict__ qB,
                                               u16* __restrict__ aA, int mode) {
  __shared__ __align__(16) u16 Asm2[40 * 512];   // subtiled, 40960 B
  __shared__ __align__(16) u16 qBs[4 * 520];
  __shared__ float sc[4][48];
  __shared__ Meta ms[40];
  __shared__ float stf[256];
  const int n = blockIdx.x, tid = threadIdx.x;
  const int wv = tid >> 6, lane = tid & 63;
  const int g = lane >> 4, cl = lane & 15;

  if (tid < 40) ms[tid] = meta[(size_t)n * 40 + tid];
  stf[tid] = tfp[tid];
  {
    int row = tid >> 6, c8 = (tid & 63) << 3;
    *(uint4*)&qBs[row * 520 + c8] =
        *(const uint4*)(qB + (size_t)n * 2048 + row * 512 + c8);
  }
  __syncthreads();

  // ---- gather A into subtiled LDS ----
  // cols 0..255: etype-selected feature row (other half zero)
  for (int it = tid; it < 320; it += 256) {
    int r = it >> 3, c0 = (it & 7) << 4;
    int et = ms[r].et;
    const u16* src = (mode == 0) ? (nm + (((size_t)ms[r].node) << 7) + c0)
                                 : (hfeat + (((size_t)(n * 40 + r)) << 7) + c0);
    uint4 w0 = *(const uint4*)src, w1 = *(const uint4*)(src + 8);
    int od = sub_off(r, et * 128 + c0), oz = sub_off(r, (1 - et) * 128 + c0);
    *(uint4*)&Asm2[od] = w0;
    *(uint4*)&Asm2[od + 8] = w1;
    *(uint4*)&Asm2[oz] = make_uint4(0, 0, 0, 0);
    *(uint4*)&Asm2[oz + 8] = make_uint4(0, 0, 0, 0);
  }
  // cols 256..383: edge features
  for (int it = tid; it < 320; it += 256) {
    int r = it >> 3, c0 = (it & 7) << 4;
    const u16* src = ef + (((size_t)ms[r].eidx) << 7) + c0;
    uint4 w0 = *(const uint4*)src, w1 = *(const uint4*)(src + 8);
    int od = sub_off(r, 256 + c0);
    *(uint4*)&Asm2[od] = w0;
    *(uint4*)&Asm2[od + 8] = w1;
  }
  // cols 384..511: time encode, balanced across all 256 lanes (20 cos each)
  {
    int d0 = (tid & 31) << 2;
    float f0 = stf[d0], f1 = stf[d0 + 1], f2 = stf[d0 + 2], f3 = stf[d0 + 3];
    float q0 = stf[128 + d0], q1 = stf[128 + d0 + 1];
    float q2 = stf[128 + d0 + 2], q3 = stf[128 + d0 + 3];
    #pragma unroll
    for (int k = 0; k < 5; ++k) {
      int r = (tid + 256 * k) >> 5;
      float dt = ms[r].dt;
      float v0 = __cosf(fmaf(dt, f0, q0));
      float v1 = __cosf(fmaf(dt, f1, q1));
      float v2 = __cosf(fmaf(dt, f2, q2));
      float v3 = __cosf(fmaf(dt, f3, q3));
      *(uint2*)&Asm2[sub_off(r, 384 + d0)] = make_uint2(pk(v0, v1), pk(v2, v3));
    }
  }
  __syncthreads();

  // ---- scores: S[row][head] via mfma 16x16x32 (waves 0..2) ----
  if (wv < 3) {
    f32x4 acc = {0.f, 0.f, 0.f, 0.f};
    const int trow = 16 * wv + cl;
    const int rowc = (trow < 40) ? trow : 0;   // clamp keeps reads in-bounds
    #pragma unroll
    for (int k0 = 0; k0 < 512; k0 += 32) {
      int ca = k0 + 8 * g;
      bf16x8 af = *(const bf16x8*)&Asm2[sub_off(rowc, ca)];
      bf16x8 bq = *(const bf16x8*)&qBs[(cl & 3) * 520 + ca];  // cols 4..15 = dup, discarded
      acc = __builtin_amdgcn_mfma_f32_16x16x32_bf16(af, bq, acc, 0, 0, 0);
    }
    if (cl < 4) {                      // D: row = 4g+j, col(head) = cl
      #pragma unroll
      for (int j = 0; j < 4; ++j) sc[cl][16 * wv + 4 * g + j] = acc[j];
    }
  }
  __syncthreads();

  // ---- softmax per head (wave = head); sc row overwritten with weights ----
  {
    const int h = wv;
    float s = -3.0e38f;
    if (lane < 40) {
      s = sc[h][lane] * 0.10206207261596575f;  // 1/sqrt(96)
      if (ms[lane].node == 0) s = -1.0e9f;
    }
    float mx = s;
    for (int o = 32; o; o >>= 1) mx = fmaxf(mx, __shfl_down(mx, o));
    mx = __shfl(mx, 0);
    float p = (lane < 40) ? expf(s - mx) : 0.f;
    float sum = p;
    for (int o = 32; o; o >>= 1) sum += __shfl_down(sum, o);
    sum = __shfl(sum, 0);
    if (lane < 40) sc[h][lane] = p / sum;
  }
  // no barrier needed: sc[wv][*] is produced and consumed by the same wave

  // ---- aA[wv][c] = sum_r sc[wv][r] * A[r][c]  (lane owns 8 contiguous cols) ----
  {
    const int c0 = lane << 3;
    float acc[8] = {};
    #pragma unroll 8
    for (int rr = 0; rr < 40; ++rr) {
      int r = rr + 9 * g; if (r >= 40) r -= 40;   // r mod 4 differs per group
      float a = sc[wv][r];
      uint4 w = *(const uint4*)&Asm2[sub_off(r, c0)];
      acc[0] += a * bf2f((u16)(w.x & 0xffffu));
      acc[1] += a * bf2f((u16)(w.x >> 16));
      acc[2] += a * bf2f((u16)(w.y & 0xffffu));
      acc[3] += a * bf2f((u16)(w.y >> 16));
      acc[4] += a * bf2f((u16)(w.z & 0xffffu));
      acc[5] += a * bf2f((u16)(w.z >> 16));
      acc[6] += a * bf2f((u16)(w.w & 0xffffu));
      acc[7] += a * bf2f((u16)(w.w >> 16));
    }
    uint4 o;
    o.x = pk(acc[0], acc[1]); o.y = pk(acc[2], acc[3]);
    o.z = pk(acc[4], acc[5]); o.w = pk(acc[6], acc[7]);
    *(uint4*)&aA[(size_t)n * 2048 + wv * 512 + c0] = o;
  }
}

// ---------- o = per-head aA @ BT_v^T  (tiled; grid {h=4, nb}) ----------
__global__ __launch_bounds__(256) void o_gemm_k(const u16* __restrict__ aA,
                                                const u16* __restrict__ BT,
                                                float* __restrict__ o) {
  __shared__ u16 As2[64][136];
  __shared__ u16 Bs2[96][136];
  const int h = blockIdx.x, n0 = blockIdx.y * 64;
  const int tid = threadIdx.x, ty = tid >> 5, tx = tid & 31;
  float acc[8][3] = {};
  for (int kc = 0; kc < 512; kc += 128) {
    __syncthreads();
    for (int i = tid; i < 64 * 128; i += 256) {
      int r = i >> 7, c = i & 127;
      As2[r][c] = aA[(size_t)(n0 + r) * 2048 + h * 512 + kc + c];
    }
    for (int i = tid; i < 96 * 128; i += 256) {
      int r = i >> 7, c = i & 127;
      Bs2[r][c] = BT[(size_t)(384 + h * 96 + r) * 512 + kc + c];
    }
    __syncthreads();
    for (int kk = 0; kk < 128; ++kk) {
      float bv[3];
      for (int i2 = 0; i2 < 3; ++i2) bv[i2] = bf2f(Bs2[tx + 32 * i2][kk]);
      for (int rr = 0; rr < 8; ++rr) {
        float av = bf2f(As2[ty * 8 + rr][kk]);
        for (int i2 = 0; i2 < 3; ++i2) acc[rr][i2] += av * bv[i2];
      }
    }
  }
  for (int rr = 0; rr < 8; ++rr)
    for (int i2 = 0; i2 < 3; ++i2)
      o[(size_t)(n0 + ty * 8 + rr) * 384 + h * 96 + tx + 32 * i2] = acc[rr][i2];
}

// ---------- fused MLP: h = relu(o@WoM1 + src@Wm1b + bm1)@Wm2 + bm2 ----------
__global__ __launch_bounds__(128) void mlp_k(const float* __restrict__ o,
                                             const float* __restrict__ src,
                                             const u16* __restrict__ WoM1,
                                             const u16* __restrict__ Wm1b,
                                             const u16* __restrict__ bm1,
                                             const u16* __restrict__ Wm2,
                                             const u16* __restrict__ bm2,
                                             u16* __restrict__ out_bf,
                                             float* __restrict__ out_f) {
  __shared__ float so[384], ss[128], su[128];
  const int n = blockIdx.x, j = threadIdx.x;
  for (int c = j; c < 384; c += 128) so[c] = o[(size_t)n * 384 + c];
  ss[j] = src[(size_t)n * 128 + j];
  __syncthreads();
  float acc = bf2f(bm1[j]);
  for (int c = 0; c < 384; ++c) acc += so[c] * bf2f(WoM1[c * 128 + j]);
  for (int c = 0; c < 128; ++c) acc += ss[c] * bf2f(Wm1b[c * 128 + j]);
  su[j] = fmaxf(acc, 0.f);
  __syncthreads();
  float acc2 = bf2f(bm2[j]);
  for (int c = 0; c < 128; ++c) acc2 += su[c] * bf2f(Wm2[c * 128 + j]);
  if (out_bf) out_bf[(size_t)n * 128 + j] = f2bf(acc2);
  else out_f[(size_t)n * 128 + j] = acc2;
}

// ---------- bilinear score + sigmoid (output dtype branched on sniff) ----------
__global__ __launch_bounds__(128) void score_k(const float* __restrict__ h2,
                                               const u16* __restrict__ Wmatch,
                                               const u16* __restrict__ bmatch,
                                               const int* __restrict__ etype,
                                               const void* tf, void* __restrict__ out) {
  __shared__ float se[128], te[128], red[128];
  const int b = blockIdx.x, e = threadIdx.x;
  se[e] = h2[b * 128 + e];
  te[e] = h2[(128 + b) * 128 + e];
  __syncthreads();
  const int et = etype[b];
  const u16* W = Wmatch + (size_t)et * 128 * 128;
  float inner = 0.f;
  for (int d = 0; d < 128; ++d) inner += se[d] * bf2f(W[d * 128 + e]);
  red[e] = inner * te[e];
  __syncthreads();
  for (int s = 64; s; s >>= 1) { if (e < s) red[e] += red[e + s]; __syncthreads(); }
  if (e == 0) {
    float v = 1.f / (1.f + expf(-(red[0] + bf2f(bmatch[et]))));
    if (sniff_bf(tf)) ((u16*)out)[b] = f2bf(v);
    else ((float*)out)[b] = v;
  }
}

extern "C" void kernel_launch(void* const* d_in, const int* in_sizes, int n_in,
                              void* d_out, int out_size, void* d_ws, size_t ws_size,
                              hipStream_t stream) {
  const int* src_idx = (const int*)d_in[0];
  const int* tgt_idx = (const int*)d_in[1];
  const void* cut_t  = d_in[2];
  const int* etype_l = (const int*)d_in[5];
  const int* nd2 = (const int*)d_in[6];
  const int* ei2 = (const int*)d_in[7];
  const void* t2 = d_in[8];
  const int* et2 = (const int*)d_in[9];
  const int* nd1 = (const int*)d_in[11];
  const int* ei1 = (const int*)d_in[12];
  const void* t1 = d_in[13];
  const int* et1 = (const int*)d_in[14];
  const void* nf  = d_in[16];
  const void* efv = d_in[17];
  const void* mem = d_in[18];
  const void* tf  = d_in[19];
  const void* tp  = d_in[20];

  char* ws = (char*)d_ws;
  size_t off = 0;
  auto alloc = [&](size_t bytes) -> char* {
    char* p = ws + off; off += (bytes + 255) & ~(size_t)255; return p;
  };
  u16*   W_c   = (u16*)alloc((size_t)NW_TOTAL * 2);
  float* tfp   = (float*)alloc(256 * 4);
  u16*   nm_bf = (u16*)alloc((size_t)400000 * 128 * 2);
  u16*   ef_bf = (u16*)alloc((size_t)200000 * 128 * 2);
  u16*   BT    = (u16*)alloc((size_t)2 * 768 * 512 * 2);
  u16*   WoM1  = (u16*)alloc((size_t)2 * 384 * 128 * 2);
  float* qb    = (float*)alloc((size_t)2 * 384 * 4);
  Meta*  meta0 = (Meta*)alloc((size_t)409600 * 16);
  Meta*  meta1 = (Meta*)alloc((size_t)10240 * 16);
  float* src1  = (float*)alloc((size_t)10240 * 128 * 4);
  float* src2  = (float*)alloc((size_t)256 * 128 * 4);
  float* qh0   = (float*)alloc((size_t)10240 * 384 * 4);
  float* qh1   = (float*)alloc((size_t)256 * 384 * 4);
  u16*   qB0   = (u16*)alloc((size_t)10240 * 2048 * 2);
  u16*   qB1   = (u16*)alloc((size_t)256 * 2048 * 2);
  u16*   aA0   = (u16*)alloc((size_t)10240 * 2048 * 2);
  u16*   aA1   = (u16*)alloc((size_t)256 * 2048 * 2);
  float* o0    = (float*)alloc((size_t)10240 * 384 * 4);
  float* o1    = (float*)alloc((size_t)256 * 384 * 4);
  u16*   h1    = (u16*)alloc((size_t)10240 * 128 * 2);
  float* h2    = (float*)alloc((size_t)256 * 128 * 4);
  if (off > ws_size) return;  // fail visibly (absmax ~0.59) if ws too small

  cvt_w_k<<<(NW_TOTAL + 255) / 256, 256, 0, stream>>>(
      d_in[21], d_in[22], d_in[23], d_in[24], d_in[25], d_in[26], d_in[27], d_in[28],
      d_in[29], d_in[30], d_in[31], tf, W_c);
  cvt_tf_k<<<1, 256, 0, stream>>>(tf, tp, tfp);
  cvt_feat_k<<<50000, 256, 0, stream>>>(nf, mem, tf, nm_bf, 12800000, 1);
  cvt_feat_k<<<25000, 256, 0, stream>>>(efv, efv, tf, ef_bf, 6400000, 0);
  build_BT_k<<<3072, 256, 0, stream>>>(W_c + oWk, W_c + oWv, W_c + oWrel, BT);
  build_WoM1_k<<<384, 256, 0, stream>>>(W_c + oWo, W_c + oWm1, WoM1);
  build_qb_k<<<3, 256, 0, stream>>>(W_c + oWq, tfp + 128, qb);
  build_meta_k<<<1600, 256, 0, stream>>>(meta0, nd1, ei1, et1, t1, t2, tf, 409600, 0);
  build_meta_k<<<40, 256, 0, stream>>>(meta1, nd2, ei2, et2, t2, cut_t, tf, 10240, 1);
  gather_src_k<<<5120, 256, 0, stream>>>(nd2, nullptr, nullptr, nm_bf, src1, 1310720, 0);
  gather_src_k<<<128, 256, 0, stream>>>(nullptr, src_idx, tgt_idx, nm_bf, src2, 32768, 1);
  qgemm_k<<<10240, 384, 0, stream>>>(src1, W_c + oWq, qb, qh0);
  qgemm_k<<<256, 384, 0, stream>>>(src2, W_c + oWq + 147456, qb + 384, qh1);
  // layer 0
  qB_gemm_k<<<dim3(4, 4, 160), 256, 0, stream>>>(qh0, BT, qB0);
  attnA_k<<<10240, 256, 0, stream>>>(meta0, nm_bf, ef_bf, h1, tfp, qB0, aA0, 0);
  o_gemm_k<<<dim3(4, 160), 256, 0, stream>>>(aA0, BT, o0);
  mlp_k<<<10240, 128, 0, stream>>>(o0, src1, WoM1, W_c + oWm1 + 384 * 128, W_c + obm1,
                                   W_c + oWm2, W_c + obm2, h1, nullptr);
  // layer 1
  qB_gemm_k<<<dim3(4, 4, 4), 256, 0, stream>>>(qh1, BT + 768 * 512, qB1);
  attnA_k<<<256, 256, 0, stream>>>(meta1, nm_bf, ef_bf, h1, tfp, qB1, aA1, 1);
  o_gemm_k<<<dim3(4, 4), 256, 0, stream>>>(aA1, BT + 768 * 512, o1);
  mlp_k<<<256, 128, 0, stream>>>(o1, src2, WoM1 + 49152, W_c + oWm1 + 65536 + 49152,
                                 W_c + obm1 + 128, W_c + oWm2 + 16384, W_c + obm2 + 128,
                                 nullptr, h2);
  score_k<<<128, 128, 0, stream>>>(h2, W_c + oWmatch, W_c + obmatch, etype_l, tf, d_out);
}